// Round 7
// baseline (549.238 us; speedup 1.0000x reference)
//
#include <hip/hip_runtime.h>
#include <hip/hip_fp16.h>

static constexpr int TPB      = 256;
static constexpr int MAXBINS  = 256;
static constexpr int BIN_SHIFT = 10;
static constexpr int BINSZ    = 1 << BIN_SHIFT;   // 1024 nodes per bin -> 12KB LDS tile
static constexpr int NBLKA    = 2048;             // count/scatter blocks
static constexpr int PERT     = NBLKA / TPB;      // hist entries per thread in scan1
static constexpr int SSL      = 8;                // slices per bin (B phase)
static constexpr int MAXG     = 64;
static constexpr int SLOTS    = MAXG * 6;         // 384 stress accumulators
static constexpr int CAP      = 16;               // LDS bucket depth per bin
static constexpr int NWAVES   = TPB / 64;

// ---------------------------------------------------------------- A1: count
__global__ __launch_bounds__(TPB) void count_kernel(
    const int* __restrict__ idx0, const int* __restrict__ idx1,
    unsigned* __restrict__ g_hist, int E, int nbins) {
    __shared__ unsigned hist[MAXBINS];
    for (int t = threadIdx.x; t < nbins; t += TPB) hist[t] = 0u;
    __syncthreads();

    const int NG = E >> 2;
    const int GC = (NG + NBLKA - 1) / NBLKA;
    const int g0 = blockIdx.x * GC;
    int g1 = g0 + GC; if (g1 > NG) g1 = NG;
    const int4* i04 = (const int4*)idx0;
    const int4* i14 = (const int4*)idx1;

    for (int k = g0 + threadIdx.x; k < g1; k += TPB) {
        int4 a = i04[k], b = i14[k];
        atomicAdd(&hist[((unsigned)a.x) >> BIN_SHIFT], 1u);
        atomicAdd(&hist[((unsigned)a.y) >> BIN_SHIFT], 1u);
        atomicAdd(&hist[((unsigned)a.z) >> BIN_SHIFT], 1u);
        atomicAdd(&hist[((unsigned)a.w) >> BIN_SHIFT], 1u);
        atomicAdd(&hist[((unsigned)b.x) >> BIN_SHIFT], 1u);
        atomicAdd(&hist[((unsigned)b.y) >> BIN_SHIFT], 1u);
        atomicAdd(&hist[((unsigned)b.z) >> BIN_SHIFT], 1u);
        atomicAdd(&hist[((unsigned)b.w) >> BIN_SHIFT], 1u);
    }
    if (blockIdx.x == 0) {  // scalar tail (E % 4)
        for (int e = (NG << 2) + threadIdx.x; e < E; e += TPB) {
            atomicAdd(&hist[((unsigned)idx0[e]) >> BIN_SHIFT], 1u);
            atomicAdd(&hist[((unsigned)idx1[e]) >> BIN_SHIFT], 1u);
        }
    }
    __syncthreads();
    for (int t = threadIdx.x; t < nbins; t += TPB)
        g_hist[(size_t)t * NBLKA + blockIdx.x] = hist[t];
}

// ----------------------------------------------- SCAN 1: per-bin block scan
__global__ __launch_bounds__(TPB) void scan1_kernel(
    unsigned* __restrict__ g_hist, unsigned* __restrict__ bin_tot) {
    unsigned* row = g_hist + (size_t)blockIdx.x * NBLKA;
    __shared__ unsigned s[TPB];
    unsigned v[PERT];
    unsigned sum = 0;
    const int base = threadIdx.x * PERT;
#pragma unroll
    for (int j = 0; j < PERT; ++j) { v[j] = row[base + j]; sum += v[j]; }
    s[threadIdx.x] = sum;
    __syncthreads();
    for (int off = 1; off < TPB; off <<= 1) {
        unsigned t = (threadIdx.x >= off) ? s[threadIdx.x - off] : 0u;
        __syncthreads();
        s[threadIdx.x] += t;
        __syncthreads();
    }
    unsigned run = s[threadIdx.x] - sum;   // exclusive
#pragma unroll
    for (int j = 0; j < PERT; ++j) { unsigned o = v[j]; row[base + j] = run; run += o; }
    if (threadIdx.x == TPB - 1) bin_tot[blockIdx.x] = s[TPB - 1];
}

// ----------------------------------------------- SCAN 2: bin bases (1 block)
__global__ __launch_bounds__(TPB) void scan2_kernel(
    const unsigned* __restrict__ bin_tot, unsigned* __restrict__ bin_base,
    unsigned* __restrict__ bin_count, int nbins, int gsize) {
    __shared__ unsigned tot[MAXBINS], base[MAXBINS];
    for (int t = threadIdx.x; t < nbins; t += TPB) tot[t] = bin_tot[t];
    __syncthreads();
    if (threadIdx.x == 0) {
        unsigned run = 0;
        for (int i = 0; i < nbins; ++i) {
            if (i % gsize == 0) run = 0;   // offsets restart at each pass-group
            base[i] = run; run += tot[i];
        }
    }
    __syncthreads();
    for (int t = threadIdx.x; t < nbins; t += TPB) {
        bin_base[t] = base[t];
        bin_count[t] = tot[t];
    }
}

// ------------------------------------------------------------- A3: scatter
__device__ inline void emit_rec(uint2* __restrict__ rec,
                                unsigned* __restrict__ off, unsigned* __restrict__ cnt,
                                uint2* __restrict__ buf,
                                int node, float fx, float fy, float fz,
                                int binLo, int binHi) {
    int bb = node >> BIN_SHIFT;
    if (bb >= binLo && bb < binHi) {
        unsigned lid = (unsigned)node & (BINSZ - 1);
        unsigned w0 = (unsigned)__half_as_ushort(__float2half(fx)) |
                      ((unsigned)__half_as_ushort(__float2half(fy)) << 16);
        unsigned w1 = (unsigned)__half_as_ushort(__float2half(fz)) | (lid << 16);
        unsigned slot = atomicAdd(&cnt[bb], 1u);
        if (slot < (unsigned)CAP) buf[bb * CAP + slot] = make_uint2(w0, w1);
        else rec[off[bb] + slot] = make_uint2(w0, w1);   // rare overflow, exact slot
    }
}

template <bool FIRST>
__global__ __launch_bounds__(TPB) void scatter_kernel(
    const float* __restrict__ rij, const float* __restrict__ fij,
    const int* __restrict__ idx0, const int* __restrict__ idx1,
    const int* __restrict__ batch,
    const unsigned* __restrict__ g_hist, const unsigned* __restrict__ bin_base,
    uint2* __restrict__ rec, float* __restrict__ apart,
    int E, int nbins, int binLo, int binHi) {
    __shared__ unsigned off[MAXBINS];
    __shared__ unsigned cnt[MAXBINS];
    __shared__ uint2 buf[MAXBINS * CAP];
    __shared__ float s_acc[SLOTS];

    for (int t = threadIdx.x; t < nbins; t += TPB) {
        off[t] = bin_base[t] + g_hist[(size_t)t * NBLKA + blockIdx.x];
        cnt[t] = 0u;
    }
    if (FIRST)
        for (int t = threadIdx.x; t < SLOTS; t += TPB) s_acc[t] = 0.0f;
    __syncthreads();

    const int NG = E >> 2;
    const int GC = (NG + NBLKA - 1) / NBLKA;
    const int g0 = blockIdx.x * GC;
    int g1 = g0 + GC; if (g1 > NG) g1 = NG;
    const int span = g1 - g0;
    const int niter = span > 0 ? (span + TPB - 1) / TPB : 0;

    const float4* fij4 = (const float4*)fij;
    const float4* rij4 = (const float4*)rij;
    const int4* i04 = (const int4*)idx0;
    const int4* i14 = (const int4*)idx1;

    const int wid = threadIdx.x >> 6, lane = threadIdx.x & 63;

    for (int it = 0; it < niter; ++it) {
        int k = g0 + it * TPB + threadIdx.x;
        if (k < g1) {
            float4 fa = fij4[3 * k], fb = fij4[3 * k + 1], fc = fij4[3 * k + 2];
            int4 i0 = i04[k], i1 = i14[k];
            float fx[4] = {fa.x, fa.w, fb.z, fc.y};
            float fy[4] = {fa.y, fb.x, fb.w, fc.z};
            float fz[4] = {fa.z, fb.y, fc.x, fc.w};
            int s[4] = {i0.x, i0.y, i0.z, i0.w};
            int r[4] = {i1.x, i1.y, i1.z, i1.w};

#pragma unroll
            for (int e = 0; e < 4; ++e) {
                emit_rec(rec, off, cnt, buf, s[e], fx[e], fy[e], fz[e], binLo, binHi);
                emit_rec(rec, off, cnt, buf, r[e], -fx[e], -fy[e], -fz[e], binLo, binHi);
            }
            if (FIRST) {
                float4 ra = rij4[3 * k], rb = rij4[3 * k + 1], rc = rij4[3 * k + 2];
                float rx[4] = {ra.x, ra.w, rb.z, rc.y};
                float ry[4] = {ra.y, rb.x, rb.w, rc.z};
                float rz[4] = {ra.z, rb.y, rc.x, rc.w};
#pragma unroll
                for (int e = 0; e < 4; ++e) {
                    int g = batch[r[e]];
                    float* a = &s_acc[6 * g];
                    atomicAdd(&a[0], rx[e] * fx[e]);
                    atomicAdd(&a[1], ry[e] * fy[e]);
                    atomicAdd(&a[2], rz[e] * fz[e]);
                    atomicAdd(&a[3], rx[e] * fy[e]);
                    atomicAdd(&a[4], ry[e] * fz[e]);
                    atomicAdd(&a[5], rz[e] * fx[e]);
                }
            }
        }
        __syncthreads();
        // wave-cooperative coalesced flush of staged buckets
        for (int b = wid; b < nbins; b += NWAVES) {
            unsigned c = cnt[b];
            if (c == 0u) continue;
            unsigned base = off[b];
            unsigned m = c < (unsigned)CAP ? c : (unsigned)CAP;
            if ((unsigned)lane < m) rec[base + lane] = buf[b * CAP + lane];
            if (lane == 0) { off[b] = base + c; cnt[b] = 0u; }
        }
        __syncthreads();
    }

    // scalar tail (E % 4): block 0 only, exact-slot direct stores
    if (blockIdx.x == 0) {
        for (int e = (NG << 2) + threadIdx.x; e < E; e += TPB) {
            float gx = fij[3 * e], gy = fij[3 * e + 1], gz = fij[3 * e + 2];
            int si = idx0[e], ri = idx1[e];
            int b0 = si >> BIN_SHIFT;
            if (b0 >= binLo && b0 < binHi) {
                unsigned slot = atomicAdd(&cnt[b0], 1u);
                unsigned lid = (unsigned)si & (BINSZ - 1);
                unsigned w0 = (unsigned)__half_as_ushort(__float2half(gx)) |
                              ((unsigned)__half_as_ushort(__float2half(gy)) << 16);
                unsigned w1 = (unsigned)__half_as_ushort(__float2half(gz)) | (lid << 16);
                rec[off[b0] + slot] = make_uint2(w0, w1);
            }
            int b1 = ri >> BIN_SHIFT;
            if (b1 >= binLo && b1 < binHi) {
                unsigned slot = atomicAdd(&cnt[b1], 1u);
                unsigned lid = (unsigned)ri & (BINSZ - 1);
                unsigned w0 = (unsigned)__half_as_ushort(__float2half(-gx)) |
                              ((unsigned)__half_as_ushort(__float2half(-gy)) << 16);
                unsigned w1 = (unsigned)__half_as_ushort(__float2half(-gz)) | (lid << 16);
                rec[off[b1] + slot] = make_uint2(w0, w1);
            }
            if (FIRST) {
                float ex = rij[3 * e], ey = rij[3 * e + 1], ez = rij[3 * e + 2];
                int g = batch[ri];
                float* a = &s_acc[6 * g];
                atomicAdd(&a[0], ex * gx);
                atomicAdd(&a[1], ey * gy);
                atomicAdd(&a[2], ez * gz);
                atomicAdd(&a[3], ex * gy);
                atomicAdd(&a[4], ey * gz);
                atomicAdd(&a[5], ez * gx);
            }
        }
    }

    if (FIRST) {
        __syncthreads();
        for (int t = threadIdx.x; t < SLOTS; t += TPB)
            apart[(size_t)t * NBLKA + blockIdx.x] = s_acc[t];   // transposed
    }
}

// ------------------------------------------------------------- B: accumulate
__global__ __launch_bounds__(TPB) void bin_accum_kernel(
    const uint2* __restrict__ rec,
    const unsigned* __restrict__ bin_base, const unsigned* __restrict__ bin_count,
    float* __restrict__ bpart, int binLo, int nbins, int G) {
    __shared__ float lf[BINSZ * 3];
    const int brel = blockIdx.x % G;
    const int s = blockIdx.x / G;
    const int bin = binLo + brel;

    float4* lf4 = (float4*)lf;
    for (int t = threadIdx.x; t < BINSZ * 3 / 4; t += TPB)
        lf4[t] = make_float4(0.f, 0.f, 0.f, 0.f);
    __syncthreads();

    if (bin < nbins) {
        unsigned base = bin_base[bin], cnt = bin_count[bin];
        unsigned chunk = (cnt + SSL - 1) / SSL;
        unsigned r0 = (unsigned)s * chunk;
        unsigned r1 = r0 + chunk; if (r1 > cnt) r1 = cnt;
#pragma unroll 4
        for (unsigned r = r0 + threadIdx.x; r < r1; r += TPB) {
            uint2 w = rec[(size_t)base + r];
            unsigned lid = w.y >> 16;
            float fx = __half2float(__ushort_as_half((unsigned short)(w.x & 0xffffu)));
            float fy = __half2float(__ushort_as_half((unsigned short)(w.x >> 16)));
            float fz = __half2float(__ushort_as_half((unsigned short)(w.y & 0xffffu)));
            atomicAdd(&lf[lid * 3 + 0], fx);
            atomicAdd(&lf[lid * 3 + 1], fy);
            atomicAdd(&lf[lid * 3 + 2], fz);
        }
    }
    __syncthreads();
    float4* dst = (float4*)(bpart + (size_t)blockIdx.x * (BINSZ * 3));
    for (int t = threadIdx.x; t < BINSZ * 3 / 4; t += TPB) dst[t] = lf4[t];
}

// ------------------------------------------------------------- C: force out
__global__ __launch_bounds__(TPB) void force_kernel(
    const float* __restrict__ bpart, const float* __restrict__ pos_grad,
    float* __restrict__ force, long i0, long i1, int G) {
    long idx = i0 + (long)blockIdx.x * TPB + threadIdx.x;
    const long gs = (long)gridDim.x * TPB;
    for (long i = idx; i < i1; i += gs) {
        long iloc = i - i0;
        int brel = (int)(iloc / (BINSZ * 3));
        int rem = (int)(iloc - (long)brel * (BINSZ * 3));
        float acc = -pos_grad[i];
#pragma unroll
        for (int s = 0; s < SSL; ++s)
            acc += bpart[(size_t)(s * G + brel) * (BINSZ * 3) + rem];
        force[i] = acc;
    }
}

// ------------------------------------------------------------- R: stress out
__global__ __launch_bounds__(TPB) void stress_kernel(
    const float* __restrict__ apart,
    const float* __restrict__ cell_grad, const float* __restrict__ les_cell,
    const float* __restrict__ vol, float* __restrict__ stress, int slots) {
    int t = blockIdx.x;
    if (t >= slots) return;
    __shared__ float red[TPB];
    float s = 0.f;
    const float* row = apart + (size_t)t * NBLKA;
    for (int j = threadIdx.x; j < NBLKA; j += TPB) s += row[j];
    red[threadIdx.x] = s;
    __syncthreads();
    for (int w = TPB / 2; w > 0; w >>= 1) {
        if (threadIdx.x < w) red[threadIdx.x] += red[threadIdx.x + w];
        __syncthreads();
    }
    if (threadIdx.x == 0) {
        int g = t / 6, c = t - 6 * g;
        const int va[6] = {0, 1, 2, 0, 1, 0};
        const int vb[6] = {0, 1, 2, 1, 2, 2};
        int a = va[c], bb = vb[c];
        const float* L = les_cell + 9 * g;
        const float* Gm = cell_grad + 9 * g;
        float lr = L[a] * Gm[bb] + L[3 + a] * Gm[3 + bb] + L[6 + a] * Gm[6 + bb];
        stress[t] = (-red[0] - lr) / vol[g];
    }
}

// ---------------------------------------------------- fallback (round-1 path)
__global__ void init_force_kernel(const float4* __restrict__ pg4,
                                  float4* __restrict__ f4, int n4,
                                  const float* __restrict__ pg,
                                  float* __restrict__ f, int n) {
    int i = blockIdx.x * blockDim.x + threadIdx.x;
    int s = gridDim.x * blockDim.x;
    for (int k = i; k < n4; k += s) {
        float4 v = pg4[k];
        f4[k] = make_float4(-v.x, -v.y, -v.z, -v.w);
    }
    for (int k = n4 * 4 + i; k < n; k += s) f[k] = -pg[k];
}

__global__ __launch_bounds__(256) void edge_dev_kernel(
    const float* __restrict__ rij, const float* __restrict__ fij,
    const int* __restrict__ idx0, const int* __restrict__ idx1,
    const int* __restrict__ batch,
    float* __restrict__ force, float* __restrict__ partials, int E) {
    __shared__ float s_acc[SLOTS];
    for (int t = threadIdx.x; t < SLOTS; t += blockDim.x) s_acc[t] = 0.0f;
    __syncthreads();
    const int stride = gridDim.x * blockDim.x;
    const int tid0 = blockIdx.x * blockDim.x + threadIdx.x;
    for (int e = tid0; e < E; e += stride) {
        float ex = rij[3 * e], ey = rij[3 * e + 1], ez = rij[3 * e + 2];
        float gx = fij[3 * e], gy = fij[3 * e + 1], gz = fij[3 * e + 2];
        int si = idx0[e], ri = idx1[e];
        atomicAdd(&force[3 * si + 0], gx);
        atomicAdd(&force[3 * si + 1], gy);
        atomicAdd(&force[3 * si + 2], gz);
        atomicAdd(&force[3 * ri + 0], -gx);
        atomicAdd(&force[3 * ri + 1], -gy);
        atomicAdd(&force[3 * ri + 2], -gz);
        int g = batch[ri];
        float* a = &s_acc[6 * g];
        atomicAdd(&a[0], ex * gx);
        atomicAdd(&a[1], ey * gy);
        atomicAdd(&a[2], ez * gz);
        atomicAdd(&a[3], ex * gy);
        atomicAdd(&a[4], ey * gz);
        atomicAdd(&a[5], ez * gx);
    }
    __syncthreads();
    for (int t = threadIdx.x; t < SLOTS; t += blockDim.x)
        partials[(size_t)blockIdx.x * SLOTS + t] = s_acc[t];
}

__global__ void reduce_finalize_kernel(const float* __restrict__ partials, int nblocks,
                                       const float* __restrict__ cell_grad,
                                       const float* __restrict__ les_cell,
                                       const float* __restrict__ vol,
                                       float* __restrict__ stress_out, int slots) {
    int t = blockIdx.x * blockDim.x + threadIdx.x;
    if (t >= slots) return;
    float s = 0.0f;
    for (int b = 0; b < nblocks; ++b) s += partials[(size_t)b * SLOTS + t];
    int g = t / 6, c = t - 6 * g;
    const int va[6] = {0, 1, 2, 0, 1, 0};
    const int vb[6] = {0, 1, 2, 1, 2, 2};
    int a = va[c], bb = vb[c];
    const float* L = les_cell + 9 * g;
    const float* G = cell_grad + 9 * g;
    float lr = L[a] * G[bb] + L[3 + a] * G[3 + bb] + L[6 + a] * G[6 + bb];
    stress_out[t] = (-s - lr) / vol[g];
}

// ------------------------------------------------------------------ launcher
static inline size_t alignup(size_t x) { return (x + 255) & ~(size_t)255; }

extern "C" void kernel_launch(void* const* d_in, const int* in_sizes, int n_in,
                              void* d_out, int out_size, void* d_ws, size_t ws_size,
                              hipStream_t stream) {
    const float* rij = (const float*)d_in[0];
    const float* fij = (const float*)d_in[1];
    const float* pos_grad = (const float*)d_in[2];
    const float* cell_grad = (const float*)d_in[3];
    const float* les_cell = (const float*)d_in[4];
    const float* vol = (const float*)d_in[5];
    const int* edge_idx = (const int*)d_in[6];
    const int* batch = (const int*)d_in[7];

    const int E = in_sizes[0] / 3;
    const int N = in_sizes[2] / 3;
    const int ngr = in_sizes[5];
    const int slots = 6 * ngr;

    float* force = (float*)d_out;
    float* stress = (float*)d_out + (size_t)N * 3;

    const int nbins = (N + BINSZ - 1) >> BIN_SHIFT;

    // pick smallest P (passes over node-groups) whose scratch fits ws
    int P = -1, G = 0; size_t cap = 0;
    size_t o_rec = 0, o_hist = 0, o_tot = 0, o_base = 0, o_cnt = 0, o_apart = 0, o_bpart = 0;
    if (nbins <= MAXBINS && ngr <= MAXG && E >= 4) {
        for (int p : {1, 2, 4, 8, 16}) {
            int g = (nbins + p - 1) / p;
            double share = (double)g * BINSZ / (double)N;
            if (share > 1.0) share = 1.0;
            size_t c = (size_t)(2.0 * (double)E * share * 1.03) + 8192;
            if (c > 2 * (size_t)E) c = 2 * (size_t)E;
            size_t off = 0;
            o_rec = off;   off += alignup(c * 8);
            o_hist = off;  off += alignup((size_t)nbins * NBLKA * 4);
            o_tot = off;   off += alignup(MAXBINS * 4);
            o_base = off;  off += alignup(MAXBINS * 4);
            o_cnt = off;   off += alignup(MAXBINS * 4);
            o_apart = off; off += alignup((size_t)SLOTS * NBLKA * 4);
            o_bpart = off; off += alignup((size_t)SSL * g * (BINSZ * 3) * 4);
            if (off <= ws_size) { P = p; G = g; cap = c; break; }
        }
    }

    if (P > 0) {
        char* ws = (char*)d_ws;
        uint2* rec = (uint2*)(ws + o_rec);
        unsigned* g_hist = (unsigned*)(ws + o_hist);
        unsigned* bin_tot = (unsigned*)(ws + o_tot);
        unsigned* bin_base = (unsigned*)(ws + o_base);
        unsigned* bin_count = (unsigned*)(ws + o_cnt);
        float* apart = (float*)(ws + o_apart);
        float* bpart = (float*)(ws + o_bpart);

        count_kernel<<<NBLKA, TPB, 0, stream>>>(edge_idx, edge_idx + E, g_hist, E, nbins);
        scan1_kernel<<<nbins, TPB, 0, stream>>>(g_hist, bin_tot);
        scan2_kernel<<<1, TPB, 0, stream>>>(bin_tot, bin_base, bin_count, nbins, G);

        for (int p = 0; p < P; ++p) {
            const int binLo = p * G;
            if (binLo >= nbins) break;
            const int binHi = (binLo + G < nbins) ? binLo + G : nbins;

            if (p == 0)
                scatter_kernel<true><<<NBLKA, TPB, 0, stream>>>(
                    rij, fij, edge_idx, edge_idx + E, batch, g_hist, bin_base,
                    rec, apart, E, nbins, binLo, binHi);
            else
                scatter_kernel<false><<<NBLKA, TPB, 0, stream>>>(
                    rij, fij, edge_idx, edge_idx + E, batch, g_hist, bin_base,
                    rec, apart, E, nbins, binLo, binHi);

            int gcur = binHi - binLo;
            bin_accum_kernel<<<SSL * gcur, TPB, 0, stream>>>(
                rec, bin_base, bin_count, bpart, binLo, nbins, gcur);

            long i0 = (long)binLo * BINSZ * 3;
            long nhi = (long)binHi * BINSZ; if (nhi > N) nhi = N;
            long i1 = nhi * 3;
            long elems = i1 - i0;
            int cblocks = (int)((elems + TPB - 1) / TPB);
            if (cblocks > 2048) cblocks = 2048;
            if (cblocks < 1) cblocks = 1;
            force_kernel<<<cblocks, TPB, 0, stream>>>(bpart, pos_grad, force, i0, i1, gcur);
        }

        stress_kernel<<<slots, TPB, 0, stream>>>(apart, cell_grad, les_cell, vol,
                                                 stress, slots);
    } else {
        // device-atomic fallback (proven correct, slow)
        float* partials = (float*)d_ws;
        int eblocks = 512;
        size_t need = (size_t)eblocks * SLOTS * sizeof(float);
        if (need > ws_size) {
            int fit = (int)(ws_size / (SLOTS * sizeof(float)));
            eblocks = fit > 0 ? fit : 1;
        }
        int n = N * 3, n4 = n / 4;
        int blocks = (n4 + 255) / 256;
        if (blocks > 1024) blocks = 1024;
        if (blocks < 1) blocks = 1;
        init_force_kernel<<<blocks, 256, 0, stream>>>(
            (const float4*)pos_grad, (float4*)force, n4, pos_grad, force, n);
        edge_dev_kernel<<<eblocks, 256, 0, stream>>>(rij, fij, edge_idx, edge_idx + E,
                                                     batch, force, partials, E);
        reduce_finalize_kernel<<<6, 64, 0, stream>>>(partials, eblocks, cell_grad,
                                                     les_cell, vol, stress, slots);
    }
}

// Round 8
// 521.656 us; speedup vs baseline: 1.0529x; 1.0529x over previous
//
#include <hip/hip_runtime.h>
#include <hip/hip_fp16.h>

static constexpr int TPB       = 256;
static constexpr int MAXB      = 64;            // max staging bins (N <= 256K)
static constexpr int BIN_SHIFT = 12;            // 4096 nodes per staging bin
static constexpr int BINSZ     = 1 << BIN_SHIFT;
static constexpr int SUB_SHIFT = 11;            // 2048-node accum subtile (24KB LDS)
static constexpr int SUBSZ     = 1 << SUB_SHIFT;
static constexpr int NSUB      = BINSZ / SUBSZ; // 2
static constexpr int CAP       = 64;            // LDS bucket depth per bin
static constexpr int NBLKS     = 2048;          // scatter blocks
static constexpr int NBLKC     = 512;           // count blocks
static constexpr int SSL       = 16;            // record slices per (bin,subtile)
static constexpr int MAXG      = 64;
static constexpr int SLOTS     = MAXG * 6;      // 384 stress accumulators
static constexpr int NWAVES    = TPB / 64;

// ---------------------------------------------------------------- A1: count
__global__ __launch_bounds__(TPB) void count_kernel(
    const int* __restrict__ idx0, const int* __restrict__ idx1,
    unsigned* __restrict__ g_hist, int E, int nbins) {
    __shared__ unsigned hist[MAXB];
    for (int t = threadIdx.x; t < nbins; t += TPB) hist[t] = 0u;
    __syncthreads();

    const int NG = E >> 2;
    const int GC = (NG + NBLKC - 1) / NBLKC;
    const int g0 = blockIdx.x * GC;
    int g1 = g0 + GC; if (g1 > NG) g1 = NG;
    const int4* i04 = (const int4*)idx0;
    const int4* i14 = (const int4*)idx1;

    for (int k = g0 + threadIdx.x; k < g1; k += TPB) {
        int4 a = i04[k], b = i14[k];
        atomicAdd(&hist[((unsigned)a.x) >> BIN_SHIFT], 1u);
        atomicAdd(&hist[((unsigned)a.y) >> BIN_SHIFT], 1u);
        atomicAdd(&hist[((unsigned)a.z) >> BIN_SHIFT], 1u);
        atomicAdd(&hist[((unsigned)a.w) >> BIN_SHIFT], 1u);
        atomicAdd(&hist[((unsigned)b.x) >> BIN_SHIFT], 1u);
        atomicAdd(&hist[((unsigned)b.y) >> BIN_SHIFT], 1u);
        atomicAdd(&hist[((unsigned)b.z) >> BIN_SHIFT], 1u);
        atomicAdd(&hist[((unsigned)b.w) >> BIN_SHIFT], 1u);
    }
    if (blockIdx.x == 0) {  // scalar tail (E % 4)
        for (int e = (NG << 2) + threadIdx.x; e < E; e += TPB) {
            atomicAdd(&hist[((unsigned)idx0[e]) >> BIN_SHIFT], 1u);
            atomicAdd(&hist[((unsigned)idx1[e]) >> BIN_SHIFT], 1u);
        }
    }
    __syncthreads();
    for (int t = threadIdx.x; t < nbins; t += TPB)
        g_hist[(size_t)t * NBLKC + blockIdx.x] = hist[t];
}

// ------------------------------------------- SCAN: bin totals/bases (1 block)
__global__ __launch_bounds__(TPB) void scan_kernel(
    const unsigned* __restrict__ g_hist,
    unsigned* __restrict__ bin_base, unsigned* __restrict__ bin_count,
    unsigned* __restrict__ cursor, int nbins) {
    __shared__ unsigned part[TPB];
    __shared__ unsigned tot[MAXB], base[MAXB];
    int b = threadIdx.x >> 2, q = threadIdx.x & 3;
    unsigned s = 0;
    if (b < nbins)
        for (int j = q; j < NBLKC; j += 4) s += g_hist[(size_t)b * NBLKC + j];
    part[threadIdx.x] = s;
    __syncthreads();
    if (threadIdx.x < (unsigned)nbins) {
        int t4 = threadIdx.x * 4;
        tot[threadIdx.x] = part[t4] + part[t4 + 1] + part[t4 + 2] + part[t4 + 3];
    }
    __syncthreads();
    if (threadIdx.x == 0) {
        unsigned run = 0;
        for (int i = 0; i < nbins; ++i) { base[i] = run; run += tot[i]; }
    }
    __syncthreads();
    if (threadIdx.x < (unsigned)nbins) {
        bin_base[threadIdx.x] = base[threadIdx.x];
        bin_count[threadIdx.x] = tot[threadIdx.x];
        cursor[threadIdx.x] = base[threadIdx.x];
    }
}

// ------------------------------------------------------------- A3: scatter
__device__ inline uint2 pack_rec(int node, float fx, float fy, float fz) {
    unsigned lid = (unsigned)node & (BINSZ - 1);
    unsigned w0 = (unsigned)__half_as_ushort(__float2half(fx)) |
                  ((unsigned)__half_as_ushort(__float2half(fy)) << 16);
    unsigned w1 = (unsigned)__half_as_ushort(__float2half(fz)) | (lid << 16);
    return make_uint2(w0, w1);
}

__device__ inline void emit(uint2* __restrict__ rec, unsigned* __restrict__ cursor,
                            unsigned* __restrict__ cnt, uint2* __restrict__ buf,
                            int node, float fx, float fy, float fz) {
    int b = node >> BIN_SHIFT;
    uint2 w = pack_rec(node, fx, fy, fz);
    unsigned slot = atomicAdd(&cnt[b], 1u);
    if (slot < (unsigned)CAP) buf[b * CAP + slot] = w;
    else { unsigned d = atomicAdd(&cursor[b], 1u); rec[d] = w; }  // rare overflow
}

__global__ __launch_bounds__(TPB) void scatter_kernel(
    const float* __restrict__ rij, const float* __restrict__ fij,
    const int* __restrict__ idx0, const int* __restrict__ idx1,
    const int* __restrict__ batch,
    unsigned* __restrict__ cursor,
    uint2* __restrict__ rec, float* __restrict__ apart,
    int E, int nbins) {
    extern __shared__ char smem[];
    uint2* buf = (uint2*)smem;                                   // nbins*CAP
    unsigned* cnt = (unsigned*)(buf + (size_t)nbins * CAP);      // nbins
    unsigned* base_s = cnt + nbins;                              // nbins
    float* s_acc = (float*)(base_s + nbins);                     // SLOTS

    for (int t = threadIdx.x; t < nbins; t += TPB) cnt[t] = 0u;
    for (int t = threadIdx.x; t < SLOTS; t += TPB) s_acc[t] = 0.0f;
    __syncthreads();

    const int NG = E >> 2;
    const int GC = (NG + NBLKS - 1) / NBLKS;
    const int g0 = blockIdx.x * GC;
    int g1 = g0 + GC; if (g1 > NG) g1 = NG;
    const int span = g1 - g0;
    const int niter = span > 0 ? (span + TPB - 1) / TPB : 0;

    const float4* fij4 = (const float4*)fij;
    const float4* rij4 = (const float4*)rij;
    const int4* i04 = (const int4*)idx0;
    const int4* i14 = (const int4*)idx1;

    const int wid = threadIdx.x >> 6, lane = threadIdx.x & 63;

    for (int it = 0; it < niter; ++it) {
        int k = g0 + it * TPB + threadIdx.x;
        if (k < g1) {
            float4 fa = fij4[3 * k], fb = fij4[3 * k + 1], fc = fij4[3 * k + 2];
            int4 i0 = i04[k], i1 = i14[k];
            float fx[4] = {fa.x, fa.w, fb.z, fc.y};
            float fy[4] = {fa.y, fb.x, fb.w, fc.z};
            float fz[4] = {fa.z, fb.y, fc.x, fc.w};
            int s[4] = {i0.x, i0.y, i0.z, i0.w};
            int r[4] = {i1.x, i1.y, i1.z, i1.w};

#pragma unroll
            for (int e = 0; e < 4; ++e) {
                emit(rec, cursor, cnt, buf, s[e], fx[e], fy[e], fz[e]);
                emit(rec, cursor, cnt, buf, r[e], -fx[e], -fy[e], -fz[e]);
            }
            float4 ra = rij4[3 * k], rb = rij4[3 * k + 1], rc = rij4[3 * k + 2];
            float rx[4] = {ra.x, ra.w, rb.z, rc.y};
            float ry[4] = {ra.y, rb.x, rb.w, rc.z};
            float rz[4] = {ra.z, rb.y, rc.x, rc.w};
#pragma unroll
            for (int e = 0; e < 4; ++e) {
                int g = batch[r[e]];
                float* a = &s_acc[6 * g];
                atomicAdd(&a[0], rx[e] * fx[e]);
                atomicAdd(&a[1], ry[e] * fy[e]);
                atomicAdd(&a[2], rz[e] * fz[e]);
                atomicAdd(&a[3], rx[e] * fy[e]);
                atomicAdd(&a[4], ry[e] * fz[e]);
                atomicAdd(&a[5], rz[e] * fx[e]);
            }
        }
        __syncthreads();
        // F1: bulk slot reservation — one parallel vector atomic (lanes = bins)
        if (threadIdx.x < (unsigned)nbins) {
            unsigned c = cnt[threadIdx.x];
            unsigned m = c < (unsigned)CAP ? c : (unsigned)CAP;
            base_s[threadIdx.x] = m ? atomicAdd(&cursor[threadIdx.x], m) : 0u;
        }
        __syncthreads();
        // F2: coalesced wave flush (one full-wave store per bin)
        for (int b = wid; b < nbins; b += NWAVES) {
            unsigned c = cnt[b];
            unsigned m = c < (unsigned)CAP ? c : (unsigned)CAP;
            if ((unsigned)lane < m) rec[base_s[b] + lane] = buf[b * CAP + lane];
        }
        __syncthreads();
        for (int t = threadIdx.x; t < nbins; t += TPB) cnt[t] = 0u;
        __syncthreads();
    }

    // scalar tail (E % 4): block 0, direct reservation
    if (blockIdx.x == 0) {
        for (int e = (NG << 2) + threadIdx.x; e < E; e += TPB) {
            float gx = fij[3 * e], gy = fij[3 * e + 1], gz = fij[3 * e + 2];
            int si = idx0[e], ri = idx1[e];
            unsigned d0 = atomicAdd(&cursor[si >> BIN_SHIFT], 1u);
            rec[d0] = pack_rec(si, gx, gy, gz);
            unsigned d1 = atomicAdd(&cursor[ri >> BIN_SHIFT], 1u);
            rec[d1] = pack_rec(ri, -gx, -gy, -gz);
            float ex = rij[3 * e], ey = rij[3 * e + 1], ez = rij[3 * e + 2];
            int g = batch[ri];
            float* a = &s_acc[6 * g];
            atomicAdd(&a[0], ex * gx);
            atomicAdd(&a[1], ey * gy);
            atomicAdd(&a[2], ez * gz);
            atomicAdd(&a[3], ex * gy);
            atomicAdd(&a[4], ey * gz);
            atomicAdd(&a[5], ez * gx);
        }
    }

    __syncthreads();
    for (int t = threadIdx.x; t < SLOTS; t += TPB)
        apart[(size_t)t * NBLKS + blockIdx.x] = s_acc[t];   // transposed
}

// ------------------------------------------------------------- B: accumulate
__global__ __launch_bounds__(TPB) void bin_accum_kernel(
    const uint2* __restrict__ rec,
    const unsigned* __restrict__ bin_base, const unsigned* __restrict__ bin_count,
    float* __restrict__ bpart) {
    __shared__ float lf[SUBSZ * 3];                    // 24KB
    const int sl = blockIdx.x % SSL;
    const int r2 = blockIdx.x / SSL;
    const int st = r2 & (NSUB - 1);
    const int bin = r2 >> 1;                           // NSUB == 2

    float4* lf4 = (float4*)lf;
    for (int t = threadIdx.x; t < SUBSZ * 3 / 4; t += TPB)
        lf4[t] = make_float4(0.f, 0.f, 0.f, 0.f);
    __syncthreads();

    const unsigned base = bin_base[bin], cntb = bin_count[bin];
    const unsigned chunk = (cntb + SSL - 1) / SSL;
    unsigned r0 = (unsigned)sl * chunk;
    unsigned r1 = r0 + chunk; if (r1 > cntb) r1 = cntb;
    if (r0 > cntb) r0 = cntb;
#pragma unroll 4
    for (unsigned r = r0 + threadIdx.x; r < r1; r += TPB) {
        uint2 w = rec[(size_t)base + r];
        unsigned lid = w.y >> 16;
        if ((int)(lid >> SUB_SHIFT) == st) {
            unsigned l2 = lid & (SUBSZ - 1);
            float fx = __half2float(__ushort_as_half((unsigned short)(w.x & 0xffffu)));
            float fy = __half2float(__ushort_as_half((unsigned short)(w.x >> 16)));
            float fz = __half2float(__ushort_as_half((unsigned short)(w.y & 0xffffu)));
            atomicAdd(&lf[l2 * 3 + 0], fx);
            atomicAdd(&lf[l2 * 3 + 1], fy);
            atomicAdd(&lf[l2 * 3 + 2], fz);
        }
    }
    __syncthreads();
    float4* dst = (float4*)(bpart + (size_t)blockIdx.x * (SUBSZ * 3));
    for (int t = threadIdx.x; t < SUBSZ * 3 / 4; t += TPB) dst[t] = lf4[t];
}

// ------------------------------------------------------------- C: force out
__global__ __launch_bounds__(TPB) void force_kernel(
    const float* __restrict__ bpart, const float* __restrict__ pos_grad,
    float* __restrict__ force, long n3) {
    long j = (long)blockIdx.x * TPB + threadIdx.x;
    const long gs = (long)gridDim.x * TPB;
    for (; j < n3; j += gs) {
        unsigned i = (unsigned)(j / 3);
        unsigned c = (unsigned)(j - 3L * i);
        unsigned bin = i >> BIN_SHIFT;
        unsigned st = (i >> SUB_SHIFT) & (NSUB - 1);
        unsigned l2 = i & (SUBSZ - 1);
        float acc = -pos_grad[j];
        size_t tb = ((size_t)(bin * NSUB + st) * SSL) * (SUBSZ * 3) + l2 * 3 + c;
#pragma unroll
        for (int sl = 0; sl < SSL; ++sl)
            acc += bpart[tb + (size_t)sl * (SUBSZ * 3)];
        force[j] = acc;
    }
}

// ------------------------------------------------------------- R: stress out
__global__ __launch_bounds__(TPB) void stress_kernel(
    const float* __restrict__ apart,
    const float* __restrict__ cell_grad, const float* __restrict__ les_cell,
    const float* __restrict__ vol, float* __restrict__ stress, int slots) {
    int t = blockIdx.x;
    if (t >= slots) return;
    __shared__ float red[TPB];
    float s = 0.f;
    const float* row = apart + (size_t)t * NBLKS;
    for (int j = threadIdx.x; j < NBLKS; j += TPB) s += row[j];
    red[threadIdx.x] = s;
    __syncthreads();
    for (int w = TPB / 2; w > 0; w >>= 1) {
        if (threadIdx.x < w) red[threadIdx.x] += red[threadIdx.x + w];
        __syncthreads();
    }
    if (threadIdx.x == 0) {
        int g = t / 6, c = t - 6 * g;
        const int va[6] = {0, 1, 2, 0, 1, 0};
        const int vb[6] = {0, 1, 2, 1, 2, 2};
        int a = va[c], bb = vb[c];
        const float* L = les_cell + 9 * g;
        const float* Gm = cell_grad + 9 * g;
        float lr = L[a] * Gm[bb] + L[3 + a] * Gm[3 + bb] + L[6 + a] * Gm[6 + bb];
        stress[t] = (-red[0] - lr) / vol[g];
    }
}

// ---------------------------------------------------- fallback (round-1 path)
__global__ void init_force_kernel(const float4* __restrict__ pg4,
                                  float4* __restrict__ f4, int n4,
                                  const float* __restrict__ pg,
                                  float* __restrict__ f, int n) {
    int i = blockIdx.x * blockDim.x + threadIdx.x;
    int s = gridDim.x * blockDim.x;
    for (int k = i; k < n4; k += s) {
        float4 v = pg4[k];
        f4[k] = make_float4(-v.x, -v.y, -v.z, -v.w);
    }
    for (int k = n4 * 4 + i; k < n; k += s) f[k] = -pg[k];
}

__global__ __launch_bounds__(256) void edge_dev_kernel(
    const float* __restrict__ rij, const float* __restrict__ fij,
    const int* __restrict__ idx0, const int* __restrict__ idx1,
    const int* __restrict__ batch,
    float* __restrict__ force, float* __restrict__ partials, int E) {
    __shared__ float s_acc[SLOTS];
    for (int t = threadIdx.x; t < SLOTS; t += blockDim.x) s_acc[t] = 0.0f;
    __syncthreads();
    const int stride = gridDim.x * blockDim.x;
    const int tid0 = blockIdx.x * blockDim.x + threadIdx.x;
    for (int e = tid0; e < E; e += stride) {
        float ex = rij[3 * e], ey = rij[3 * e + 1], ez = rij[3 * e + 2];
        float gx = fij[3 * e], gy = fij[3 * e + 1], gz = fij[3 * e + 2];
        int si = idx0[e], ri = idx1[e];
        atomicAdd(&force[3 * si + 0], gx);
        atomicAdd(&force[3 * si + 1], gy);
        atomicAdd(&force[3 * si + 2], gz);
        atomicAdd(&force[3 * ri + 0], -gx);
        atomicAdd(&force[3 * ri + 1], -gy);
        atomicAdd(&force[3 * ri + 2], -gz);
        int g = batch[ri];
        float* a = &s_acc[6 * g];
        atomicAdd(&a[0], ex * gx);
        atomicAdd(&a[1], ey * gy);
        atomicAdd(&a[2], ez * gz);
        atomicAdd(&a[3], ex * gy);
        atomicAdd(&a[4], ey * gz);
        atomicAdd(&a[5], ez * gx);
    }
    __syncthreads();
    for (int t = threadIdx.x; t < SLOTS; t += blockDim.x)
        partials[(size_t)blockIdx.x * SLOTS + t] = s_acc[t];
}

__global__ void reduce_finalize_kernel(const float* __restrict__ partials, int nblocks,
                                       const float* __restrict__ cell_grad,
                                       const float* __restrict__ les_cell,
                                       const float* __restrict__ vol,
                                       float* __restrict__ stress_out, int slots) {
    int t = blockIdx.x * blockDim.x + threadIdx.x;
    if (t >= slots) return;
    float s = 0.0f;
    for (int b = 0; b < nblocks; ++b) s += partials[(size_t)b * SLOTS + t];
    int g = t / 6, c = t - 6 * g;
    const int va[6] = {0, 1, 2, 0, 1, 0};
    const int vb[6] = {0, 1, 2, 1, 2, 2};
    int a = va[c], bb = vb[c];
    const float* L = les_cell + 9 * g;
    const float* G = cell_grad + 9 * g;
    float lr = L[a] * G[bb] + L[3 + a] * G[3 + bb] + L[6 + a] * G[6 + bb];
    stress_out[t] = (-s - lr) / vol[g];
}

// ------------------------------------------------------------------ launcher
static inline size_t alignup(size_t x) { return (x + 255) & ~(size_t)255; }

extern "C" void kernel_launch(void* const* d_in, const int* in_sizes, int n_in,
                              void* d_out, int out_size, void* d_ws, size_t ws_size,
                              hipStream_t stream) {
    const float* rij = (const float*)d_in[0];
    const float* fij = (const float*)d_in[1];
    const float* pos_grad = (const float*)d_in[2];
    const float* cell_grad = (const float*)d_in[3];
    const float* les_cell = (const float*)d_in[4];
    const float* vol = (const float*)d_in[5];
    const int* edge_idx = (const int*)d_in[6];
    const int* batch = (const int*)d_in[7];

    const int E = in_sizes[0] / 3;
    const int N = in_sizes[2] / 3;
    const int ngr = in_sizes[5];
    const int slots = 6 * ngr;

    float* force = (float*)d_out;
    float* stress = (float*)d_out + (size_t)N * 3;

    const int nbins = (N + BINSZ - 1) >> BIN_SHIFT;
    const long N3 = (long)N * 3;

    // workspace layout
    size_t off = 0;
    const size_t o_rec = off;   off += alignup((size_t)2 * E * 8);
    const size_t o_hist = off;  off += alignup((size_t)MAXB * NBLKC * 4);
    const size_t o_base = off;  off += alignup(MAXB * 4);
    const size_t o_cnt = off;   off += alignup(MAXB * 4);
    const size_t o_cur = off;   off += alignup(MAXB * 4);
    const size_t o_apart = off; off += alignup((size_t)SLOTS * NBLKS * 4);
    const size_t o_bpart = off; off += alignup((size_t)nbins * NSUB * SSL * (SUBSZ * 3) * 4);
    const bool fit = (off <= ws_size) && (nbins <= MAXB) && (ngr <= MAXG) && (E >= 4);

    if (fit) {
        char* ws = (char*)d_ws;
        uint2* rec = (uint2*)(ws + o_rec);
        unsigned* g_hist = (unsigned*)(ws + o_hist);
        unsigned* bin_base = (unsigned*)(ws + o_base);
        unsigned* bin_count = (unsigned*)(ws + o_cnt);
        unsigned* cursor = (unsigned*)(ws + o_cur);
        float* apart = (float*)(ws + o_apart);
        float* bpart = (float*)(ws + o_bpart);

        count_kernel<<<NBLKC, TPB, 0, stream>>>(edge_idx, edge_idx + E, g_hist, E, nbins);
        scan_kernel<<<1, TPB, 0, stream>>>(g_hist, bin_base, bin_count, cursor, nbins);

        const size_t smem = (size_t)nbins * CAP * 8 + (size_t)nbins * 8 + SLOTS * 4;
        scatter_kernel<<<NBLKS, TPB, smem, stream>>>(
            rij, fij, edge_idx, edge_idx + E, batch, cursor, rec, apart, E, nbins);

        bin_accum_kernel<<<nbins * NSUB * SSL, TPB, 0, stream>>>(
            rec, bin_base, bin_count, bpart);

        int fblocks = (int)((N3 + TPB - 1) / TPB);
        if (fblocks > 4096) fblocks = 4096;
        force_kernel<<<fblocks, TPB, 0, stream>>>(bpart, pos_grad, force, N3);

        stress_kernel<<<slots, TPB, 0, stream>>>(apart, cell_grad, les_cell, vol,
                                                 stress, slots);
    } else {
        // device-atomic fallback (proven correct, slow)
        float* partials = (float*)d_ws;
        int eblocks = 512;
        size_t need = (size_t)eblocks * SLOTS * sizeof(float);
        if (need > ws_size) {
            int fit2 = (int)(ws_size / (SLOTS * sizeof(float)));
            eblocks = fit2 > 0 ? fit2 : 1;
        }
        int n = (int)N3, n4 = n / 4;
        int blocks = (n4 + 255) / 256;
        if (blocks > 1024) blocks = 1024;
        if (blocks < 1) blocks = 1;
        init_force_kernel<<<blocks, 256, 0, stream>>>(
            (const float4*)pos_grad, (float4*)force, n4, pos_grad, force, n);
        edge_dev_kernel<<<eblocks, 256, 0, stream>>>(rij, fij, edge_idx, edge_idx + E,
                                                     batch, force, partials, E);
        reduce_finalize_kernel<<<6, 64, 0, stream>>>(partials, eblocks, cell_grad,
                                                     les_cell, vol, stress, slots);
    }
}